// Round 7
// baseline (1927.963 us; speedup 1.0000x reference)
//
#include <hip/hip_runtime.h>
#include <hip/hip_bf16.h>
#include <cstddef>
#include <cstdint>

// Problem constants (match reference)
constexpr int NB    = 16;       // batch
constexpr int NN    = 2000;     // nodes per batch
constexpr int TH    = 24;       // T_HIST
constexpr int TF    = 24;       // T_FCST
constexpr int HID   = 64;
constexpr int NF    = 8;        // features
constexpr int NODES = NB * NN;      // 32000
constexpr int ETOT  = NODES * 32;   // 1,024,000 edges
constexpr int TT    = TH + TF;      // 48
constexpr int BLKN  = 64;           // nodes per block in fused kernels
constexpr int NBLK  = NODES / BLKN; // 500

__device__ __forceinline__ float sigmoidf_(float x) { return 1.f / (1.f + __expf(-x)); }
__device__ __forceinline__ float tanhf_(float x) {
    float e = __expf(2.f * x);
    return 1.f - 2.f / (e + 1.f);   // safe at +/-inf
}

__device__ __forceinline__ uint32_t f2bf(float x) {
    __hip_bfloat16 b = __float2bfloat16(x);
    uint16_t u; __builtin_memcpy(&u, &b, 2); return (uint32_t)u;
}

// ---------------- setup kernels ----------------
__global__ void k_init(float* __restrict__ dis) {
    int i = blockIdx.x * blockDim.x + threadIdx.x;
    if (i < NODES) dis[i] = 0.f;
}

__global__ void k_deg(const int* __restrict__ ei, float* __restrict__ deg) {
    int e = blockIdx.x * blockDim.x + threadIdx.x;
    if (e < ETOT) atomicAdd(&deg[ei[ETOT + e]], 1.0f);
}

// single block of 256: exclusive prefix sum of (int)degf -> row0[NODES+1], zero cnt
__global__ __launch_bounds__(256) void k_scan(const float* __restrict__ degf,
                                              int* __restrict__ row0,
                                              int* __restrict__ cnt)
{
    __shared__ int part[256];
    const int tid = threadIdx.x;
    const int per = NODES / 256;   // 125
    const int base = tid * per;
    int s = 0;
    for (int i = 0; i < per; i++) s += (int)degf[base + i];
    part[tid] = s;
    __syncthreads();
    for (int off = 1; off < 256; off <<= 1) {
        int v = (tid >= off) ? part[tid - off] : 0;
        __syncthreads();
        part[tid] += v;
        __syncthreads();
    }
    int run = (tid == 0) ? 0 : part[tid - 1];
    for (int i = 0; i < per; i++) {
        row0[base + i] = run;
        cnt[base + i]  = 0;
        run += (int)degf[base + i];
    }
    if (tid == 255) row0[NODES] = run;
}

__global__ void k_dis(float* __restrict__ dis) {
    int i = blockIdx.x * blockDim.x + threadIdx.x;
    if (i < NODES) {
        float d = dis[i];
        dis[i] = (d > 0.f) ? rsqrtf(fmaxf(d, 1.f)) : 0.f;
    }
}

// build dst-CSR with packed {src, norm} 8B records; norm computed inline
__global__ void k_fill(const int* __restrict__ ei, const float* __restrict__ dis,
                       const int* __restrict__ row0, int* __restrict__ cnt,
                       int2* __restrict__ edge8)
{
    int e = blockIdx.x * blockDim.x + threadIdx.x;
    if (e < ETOT) {
        int s = ei[e];
        int d = ei[ETOT + e];
        float nv = -(dis[s] * dis[d]);
        int p = atomicAdd(&cnt[d], 1);
        edge8[row0[d] + p] = make_int2(s, __float_as_int(nv));
    }
}

// transpose w_hh (192x64, row-major) -> Wt (64x192, k-major)
__global__ void k_prep(const float* __restrict__ whe, const float* __restrict__ whd,
                       float* __restrict__ Wte, float* __restrict__ Wtd) {
    int i = blockIdx.x * blockDim.x + threadIdx.x;   // i = k*192 + g
    if (i < 192 * 64) {
        int k = i / 192, g = i - k * 192;
        Wte[i] = whe[g * 64 + k];
        Wtd[i] = whd[g * 64 + k];
    }
}

// ---------------- fused encoder: all 24 steps in one launch ----------------
// block = 64 nodes, 256 threads. lane l = node slot, wave wv owns channels
// jA=8wv..+8 and jB=8(wv+4)..+8. h lives in LDS hx[ch][node] across steps.
__global__ __launch_bounds__(256) void k_encf(
    const float* __restrict__ pm,
    const float* __restrict__ w_ih, const float* __restrict__ Wt,
    const float* __restrict__ b_ih, const float* __restrict__ b_hh,
    const float* __restrict__ fc_w, const float* __restrict__ fc_b,
    float* __restrict__ h_fin, __hip_bfloat16* __restrict__ Hb)
{
    __shared__ float hx[HID][BLKN];
    const int l  = threadIdx.x & 63;
    const int wv = __builtin_amdgcn_readfirstlane(threadIdx.x >> 6);
    const int node = blockIdx.x * BLKN + l;
    const int jA = wv * 8, jB = (wv + 4) * 8;
    const int b = node / NN, n = node - b * NN;
    const float fcb = fc_b[0];

    for (int i = threadIdx.x; i < HID * BLKN; i += 256) ((float*)hx)[i] = 0.f;
    __syncthreads();

    for (int t = 0; t < TH; t++) {
        float aR[8], aZ[8], aN[8], bR[8], bZ[8], bN[8];
        #pragma unroll
        for (int m = 0; m < 8; m++) {
            aR[m] = b_hh[jA + m]; aZ[m] = b_hh[64 + jA + m]; aN[m] = b_hh[128 + jA + m];
            bR[m] = b_hh[jB + m]; bZ[m] = b_hh[64 + jB + m]; bN[m] = b_hh[128 + jB + m];
        }
        float axn = 0.f;
        #pragma unroll 4
        for (int k = 0; k < HID; k++) {
            const float hk = hx[k][l];
            const float* wr = Wt + k * 192;
            #pragma unroll
            for (int m = 0; m < 8; m++) {
                aR[m] = fmaf(wr[jA + m],       hk, aR[m]);
                aZ[m] = fmaf(wr[64 + jA + m],  hk, aZ[m]);
                aN[m] = fmaf(wr[128 + jA + m], hk, aN[m]);
                bR[m] = fmaf(wr[jB + m],       hk, bR[m]);
                bZ[m] = fmaf(wr[64 + jB + m],  hk, bZ[m]);
                bN[m] = fmaf(wr[128 + jB + m], hk, bN[m]);
            }
            axn = fmaf(fc_w[k], hk, axn);
        }
        const float xnv = (t > 0) ? (axn + fcb) : 0.f;
        const float pmv = pm[(b * TH + t) * NN + n];

        float hold[16];
        #pragma unroll
        for (int m = 0; m < 8; m++) { hold[m] = hx[jA + m][l]; hold[8 + m] = hx[jB + m][l]; }

        float hnew[16];
        #pragma unroll
        for (int m = 0; m < 8; m++) {
            const int j = jA + m;
            float gr = b_ih[j]       + w_ih[2 * j] * xnv         + w_ih[2 * j + 1] * pmv;
            float gz = b_ih[64 + j]  + w_ih[2 * (64 + j)] * xnv  + w_ih[2 * (64 + j) + 1] * pmv;
            float gn = b_ih[128 + j] + w_ih[2 * (128 + j)] * xnv + w_ih[2 * (128 + j) + 1] * pmv;
            float r   = sigmoidf_(gr + aR[m]);
            float z   = sigmoidf_(gz + aZ[m]);
            float nn_ = tanhf_(gn + r * aN[m]);
            hnew[m] = (1.f - z) * nn_ + z * hold[m];
        }
        #pragma unroll
        for (int m = 0; m < 8; m++) {
            const int j = jB + m;
            float gr = b_ih[j]       + w_ih[2 * j] * xnv         + w_ih[2 * j + 1] * pmv;
            float gz = b_ih[64 + j]  + w_ih[2 * (64 + j)] * xnv  + w_ih[2 * (64 + j) + 1] * pmv;
            float gn = b_ih[128 + j] + w_ih[2 * (128 + j)] * xnv + w_ih[2 * (128 + j) + 1] * pmv;
            float r   = sigmoidf_(gr + bR[m]);
            float z   = sigmoidf_(gz + bZ[m]);
            float nn_ = tanhf_(gn + r * bN[m]);
            hnew[8 + m] = (1.f - z) * nn_ + z * hold[8 + m];
        }
        __syncthreads();   // everyone done reading h_{t-1}
        #pragma unroll
        for (int m = 0; m < 8; m++) { hx[jA + m][l] = hnew[m]; hx[jB + m][l] = hnew[8 + m]; }
        __syncthreads();   // h_t visible

        *(uint4*)(Hb + (size_t)node * (TH * HID) + t * HID + jA) = make_uint4(
            f2bf(hnew[0]) | (f2bf(hnew[1]) << 16),
            f2bf(hnew[2]) | (f2bf(hnew[3]) << 16),
            f2bf(hnew[4]) | (f2bf(hnew[5]) << 16),
            f2bf(hnew[6]) | (f2bf(hnew[7]) << 16));
        *(uint4*)(Hb + (size_t)node * (TH * HID) + t * HID + jB) = make_uint4(
            f2bf(hnew[8])  | (f2bf(hnew[9])  << 16),
            f2bf(hnew[10]) | (f2bf(hnew[11]) << 16),
            f2bf(hnew[12]) | (f2bf(hnew[13]) << 16),
            f2bf(hnew[14]) | (f2bf(hnew[15]) << 16));
    }
    // final h -> h_fin (float4 kq-major), 4 coalesced stores per lane
    float4* o4 = (float4*)h_fin;
    o4[(size_t)(2 * wv)           * NODES + node] = make_float4(hx[jA][l],     hx[jA + 1][l], hx[jA + 2][l], hx[jA + 3][l]);
    o4[(size_t)(2 * wv + 1)       * NODES + node] = make_float4(hx[jA + 4][l], hx[jA + 5][l], hx[jA + 6][l], hx[jA + 7][l]);
    o4[(size_t)(2 * (wv + 4))     * NODES + node] = make_float4(hx[jB][l],     hx[jB + 1][l], hx[jB + 2][l], hx[jB + 3][l]);
    o4[(size_t)(2 * (wv + 4) + 1) * NODES + node] = make_float4(hx[jB + 4][l], hx[jB + 5][l], hx[jB + 6][l], hx[jB + 7][l]);
}

// after encoder: xn0 = fc(h_final); y1 for decoder t=0
__global__ __launch_bounds__(256) void k_fc(
    const float* __restrict__ h_in, const float* __restrict__ fc_w,
    const float* __restrict__ fc_b, const float* __restrict__ feat,
    const float* __restrict__ cw1, float* __restrict__ xn_buf,
    float* __restrict__ y1)
{
    const int node = blockIdx.x * 256 + threadIdx.x;
    if (node >= NODES) return;
    const float4* h4 = (const float4*)h_in;
    const float4* w4 = (const float4*)fc_w;
    float acc = fc_b[0];
    #pragma unroll 8
    for (int kq = 0; kq < 16; kq++) {
        const float4 v = h4[(size_t)kq * NODES + node];
        const float4 w = w4[kq];
        acc = fmaf(w.x, v.x, acc);
        acc = fmaf(w.y, v.y, acc);
        acc = fmaf(w.z, v.z, acc);
        acc = fmaf(w.w, v.w, acc);
    }
    xn_buf[node] = acc;
    const int b = node / NN, n = node - b * NN;
    const float* fp = feat + ((size_t)(b * TT + TH) * NN + n) * NF;
    float yy = acc * cw1[0];
    #pragma unroll
    for (int c = 0; c < NF; c++) yy += fp[c] * cw1[1 + c];
    y1[node] = yy;
}

// ---------------- fused decoder step: gather + GRU in one kernel ----------------
__global__ __launch_bounds__(256) void k_dec(
    const float* __restrict__ feat,
    const float* __restrict__ w_ih, const float* __restrict__ Wt,
    const float* __restrict__ b_ih, const float* __restrict__ b_hh,
    const float* __restrict__ w0, const float* __restrict__ cb,
    const float* __restrict__ xn_buf, const float* __restrict__ y1,
    const int* __restrict__ row0, const int2* __restrict__ edge8,
    const float* __restrict__ h_in, float* __restrict__ h_out,
    float* __restrict__ h_nm, int t)
{
    __shared__ float hx[HID][BLKN];
    __shared__ float gpart[4][BLKN];
    const int l  = threadIdx.x & 63;
    const int wv = __builtin_amdgcn_readfirstlane(threadIdx.x >> 6);
    const int node = blockIdx.x * BLKN + l;
    const int jA = wv * 8, jB = (wv + 4) * 8;
    const int b = node / NN, n = node - b * NN;

    // phase A: edge gather, 4 lanes per node ((na,q) remap for coalescing)
    {
        const int na = threadIdx.x >> 2;
        const int q  = threadIdx.x & 3;
        const int nd = blockIdx.x * BLKN + na;
        const int beg = row0[nd], end = row0[nd + 1];
        float acc = 0.f;
        for (int i = beg + q; i < end; i += 4) {
            const int2 e = edge8[i];
            acc = fmaf(__int_as_float(e.y), y1[e.x], acc);
        }
        gpart[q][na] = acc;
    }
    // phase A2: stage h into LDS (each wave loads 4 kq groups)
    const float4* h4 = (const float4*)h_in;
    #pragma unroll
    for (int i = 0; i < 4; i++) {
        const int kq = 4 * wv + i;
        const float4 v = h4[(size_t)kq * NODES + node];
        hx[4 * kq + 0][l] = v.x; hx[4 * kq + 1][l] = v.y;
        hx[4 * kq + 2][l] = v.z; hx[4 * kq + 3][l] = v.w;
    }
    __syncthreads();
    const float txv = gpart[0][l] + gpart[1][l] + gpart[2][l] + gpart[3][l];

    // phase B: GRU k-loop
    float aR[8], aZ[8], aN[8], bR[8], bZ[8], bN[8];
    #pragma unroll
    for (int m = 0; m < 8; m++) {
        aR[m] = b_hh[jA + m]; aZ[m] = b_hh[64 + jA + m]; aN[m] = b_hh[128 + jA + m];
        bR[m] = b_hh[jB + m]; bZ[m] = b_hh[64 + jB + m]; bN[m] = b_hh[128 + jB + m];
    }
    #pragma unroll 4
    for (int k = 0; k < HID; k++) {
        const float hk = hx[k][l];
        const float* wr = Wt + k * 192;
        #pragma unroll
        for (int m = 0; m < 8; m++) {
            aR[m] = fmaf(wr[jA + m],       hk, aR[m]);
            aZ[m] = fmaf(wr[64 + jA + m],  hk, aZ[m]);
            aN[m] = fmaf(wr[128 + jA + m], hk, aN[m]);
            bR[m] = fmaf(wr[jB + m],       hk, bR[m]);
            bZ[m] = fmaf(wr[64 + jB + m],  hk, bZ[m]);
            bN[m] = fmaf(wr[128 + jB + m], hk, bN[m]);
        }
    }

    const float xnv = xn_buf[node];
    float f[NF];
    const float* fp = feat + ((size_t)(b * TT + TH + t) * NN + n) * NF;
    #pragma unroll
    for (int q = 0; q < NF; q++) f[q] = fp[q];
    float xw = xnv * w0[0];
    #pragma unroll
    for (int q = 0; q < NF; q++) xw = fmaf(f[q], w0[1 + q], xw);
    const float xg = sigmoidf_(xw + txv + cb[0]);

    float hold[16];
    #pragma unroll
    for (int m = 0; m < 8; m++) { hold[m] = hx[jA + m][l]; hold[8 + m] = hx[jB + m][l]; }

    float hnew[16];
    #pragma unroll
    for (int m = 0; m < 8; m++) {
        const int j = jA + m;
        const float* ir  = w_ih + j * 10;
        const float* iz  = w_ih + (64 + j) * 10;
        const float* in_ = w_ih + (128 + j) * 10;
        float gr = b_ih[j] + ir[0] * xnv, gz = b_ih[64 + j] + iz[0] * xnv, gn = b_ih[128 + j] + in_[0] * xnv;
        #pragma unroll
        for (int q = 0; q < NF; q++) {
            gr = fmaf(ir[1 + q],  f[q], gr);
            gz = fmaf(iz[1 + q],  f[q], gz);
            gn = fmaf(in_[1 + q], f[q], gn);
        }
        gr = fmaf(ir[9], xg, gr); gz = fmaf(iz[9], xg, gz); gn = fmaf(in_[9], xg, gn);
        float r = sigmoidf_(gr + aR[m]);
        float z = sigmoidf_(gz + aZ[m]);
        float nn_ = tanhf_(gn + r * aN[m]);
        hnew[m] = (1.f - z) * nn_ + z * hold[m];
    }
    #pragma unroll
    for (int m = 0; m < 8; m++) {
        const int j = jB + m;
        const float* ir  = w_ih + j * 10;
        const float* iz  = w_ih + (64 + j) * 10;
        const float* in_ = w_ih + (128 + j) * 10;
        float gr = b_ih[j] + ir[0] * xnv, gz = b_ih[64 + j] + iz[0] * xnv, gn = b_ih[128 + j] + in_[0] * xnv;
        #pragma unroll
        for (int q = 0; q < NF; q++) {
            gr = fmaf(ir[1 + q],  f[q], gr);
            gz = fmaf(iz[1 + q],  f[q], gz);
            gn = fmaf(in_[1 + q], f[q], gn);
        }
        gr = fmaf(ir[9], xg, gr); gz = fmaf(iz[9], xg, gz); gn = fmaf(in_[9], xg, gn);
        float r = sigmoidf_(gr + bR[m]);
        float z = sigmoidf_(gz + bZ[m]);
        float nn_ = tanhf_(gn + r * bN[m]);
        hnew[8 + m] = (1.f - z) * nn_ + z * hold[8 + m];
    }

    const float4 q0 = make_float4(hnew[0],  hnew[1],  hnew[2],  hnew[3]);
    const float4 q1 = make_float4(hnew[4],  hnew[5],  hnew[6],  hnew[7]);
    const float4 q2 = make_float4(hnew[8],  hnew[9],  hnew[10], hnew[11]);
    const float4 q3 = make_float4(hnew[12], hnew[13], hnew[14], hnew[15]);
    float4* o4 = (float4*)h_out;
    o4[(size_t)(2 * wv)           * NODES + node] = q0;
    o4[(size_t)(2 * wv + 1)       * NODES + node] = q1;
    o4[(size_t)(2 * (wv + 4))     * NODES + node] = q2;
    o4[(size_t)(2 * (wv + 4) + 1) * NODES + node] = q3;
    float4* nm4 = (float4*)h_nm;
    nm4[(size_t)node * 16 + 2 * wv]           = q0;
    nm4[(size_t)node * 16 + 2 * wv + 1]       = q1;
    nm4[(size_t)node * 16 + 2 * (wv + 4)]     = q2;
    nm4[(size_t)node * 16 + 2 * (wv + 4) + 1] = q3;
}

// attention + out-projection + y1 prep for next step. Wave per node.
__global__ __launch_bounds__(256) void k_attn(
    const __hip_bfloat16* __restrict__ Hb, const float* __restrict__ h_nm,
    const float* __restrict__ out_w, const float* __restrict__ out_b,
    const float* __restrict__ feat, const float* __restrict__ cw1,
    float* __restrict__ xn_buf, float* __restrict__ y1,
    float* __restrict__ out, int t)
{
    const int wid  = threadIdx.x >> 6;
    const int lane = threadIdx.x & 63;
    const int node = blockIdx.x * 4 + wid;
    if (node >= NODES) return;
    const int d0 = (lane & 7) * 8;     // channel block this lane owns

    const float hj = h_nm[(size_t)node * HID + lane];
    float hval[8];
    #pragma unroll
    for (int q = 0; q < 8; q++) hval[q] = __shfl(hj, d0 + q, 64);

    const uint4* Hrow = (const uint4*)(Hb + (size_t)node * (TH * HID));
    float Hf[3][8];
    float er[3];
    #pragma unroll
    for (int R = 0; R < 3; R++) {
        const uint4 v = Hrow[R * 64 + lane];
        const uint32_t u0 = v.x, u1 = v.y, u2 = v.z, u3 = v.w;
        Hf[R][0] = __uint_as_float(u0 << 16);
        Hf[R][1] = __uint_as_float(u0 & 0xffff0000u);
        Hf[R][2] = __uint_as_float(u1 << 16);
        Hf[R][3] = __uint_as_float(u1 & 0xffff0000u);
        Hf[R][4] = __uint_as_float(u2 << 16);
        Hf[R][5] = __uint_as_float(u2 & 0xffff0000u);
        Hf[R][6] = __uint_as_float(u3 << 16);
        Hf[R][7] = __uint_as_float(u3 & 0xffff0000u);
        float part = 0.f;
        #pragma unroll
        for (int q = 0; q < 8; q++) part = fmaf(Hf[R][q], hval[q], part);
        part += __shfl_xor(part, 1, 64);
        part += __shfl_xor(part, 2, 64);
        part += __shfl_xor(part, 4, 64);
        er[R] = part;
    }

    float m = fmaxf(fmaxf(er[0], er[1]), er[2]);
    m = fmaxf(m, __shfl_xor(m, 8, 64));
    m = fmaxf(m, __shfl_xor(m, 16, 64));
    m = fmaxf(m, __shfl_xor(m, 32, 64));

    float w0_ = __expf(er[0] - m);
    float w1_ = __expf(er[1] - m);
    float w2_ = __expf(er[2] - m);
    float s = w0_ + w1_ + w2_;
    s += __shfl_xor(s, 8, 64);
    s += __shfl_xor(s, 16, 64);
    s += __shfl_xor(s, 32, 64);
    const float rs = 1.f / s;

    float aq[8];
    #pragma unroll
    for (int q = 0; q < 8; q++) {
        float a = w0_ * Hf[0][q];
        a = fmaf(w1_, Hf[1][q], a);
        a = fmaf(w2_, Hf[2][q], a);
        a += __shfl_xor(a, 8, 64);
        a += __shfl_xor(a, 16, 64);
        a += __shfl_xor(a, 32, 64);
        aq[q] = a * rs;
    }

    float part = 0.f;
    #pragma unroll
    for (int q = 0; q < 8; q++) {
        part = fmaf(out_w[d0 + q],       aq[q],   part);
        part = fmaf(out_w[HID + d0 + q], hval[q], part);
    }
    part += __shfl_xor(part, 1, 64);
    part += __shfl_xor(part, 2, 64);
    part += __shfl_xor(part, 4, 64);
    const float xnew = part + out_b[0];

    if (lane == 0) {
        const int b = node / NN, n = node - b * NN;
        out[(b * TF + t) * NN + n] = xnew;
        xn_buf[node] = xnew;
        if (t + 1 < TF) {
            const float* fp = feat + ((size_t)(b * TT + TH + t + 1) * NN + n) * NF;
            float yy = xnew * cw1[0];
            #pragma unroll
            for (int c = 0; c < NF; c++) yy += fp[c] * cw1[1 + c];
            y1[node] = yy;
        }
    }
}

// ---------------- host launch ----------------
extern "C" void kernel_launch(void* const* d_in, const int* in_sizes, int n_in,
                              void* d_out, int out_size, void* d_ws, size_t ws_size,
                              hipStream_t stream)
{
    const float* pm     = (const float*)d_in[0];
    const float* feat   = (const float*)d_in[1];
    const int*   ei     = (const int*)d_in[2];
    const float* w_ih_e = (const float*)d_in[3];
    const float* w_hh_e = (const float*)d_in[4];
    const float* b_ih_e = (const float*)d_in[5];
    const float* b_hh_e = (const float*)d_in[6];
    const float* fc_w   = (const float*)d_in[7];
    const float* fc_b   = (const float*)d_in[8];
    const float* cw0    = (const float*)d_in[9];
    const float* cw1    = (const float*)d_in[10];
    const float* cb     = (const float*)d_in[11];
    const float* w_ih_d = (const float*)d_in[12];
    const float* w_hh_d = (const float*)d_in[13];
    const float* b_ih_d = (const float*)d_in[14];
    const float* b_hh_d = (const float*)d_in[15];
    const float* out_w  = (const float*)d_in[16];
    const float* out_b  = (const float*)d_in[17];
    float* out = (float*)d_out;

    char* ws = (char*)d_ws;
    size_t off = 0;
    auto alloc = [&](size_t bytes) -> void* {
        void* p = ws + off;
        off += (bytes + 255) & ~(size_t)255;
        return p;
    };
    float* hA   = (float*)alloc(sizeof(float) * HID * NODES);
    float* hB   = (float*)alloc(sizeof(float) * HID * NODES);
    float* h_nm = (float*)alloc(sizeof(float) * HID * NODES);
    __hip_bfloat16* Hb = (__hip_bfloat16*)alloc(sizeof(__hip_bfloat16) * (size_t)NODES * TH * HID);
    float* xn   = (float*)alloc(sizeof(float) * NODES);
    float* dis  = (float*)alloc(sizeof(float) * NODES);
    float* y1   = (float*)alloc(sizeof(float) * NODES);
    float* WtE  = (float*)alloc(sizeof(float) * 192 * 64);
    float* WtD  = (float*)alloc(sizeof(float) * 192 * 64);
    int*   row0 = (int*)alloc(sizeof(int) * (NODES + 1));
    int*   cnt  = (int*)alloc(sizeof(int) * NODES);
    int2*  edge8 = (int2*)alloc(sizeof(int2) * ETOT);
    if (off > ws_size) return;  // visible failure instead of corruption

    // setup
    k_init<<<(NODES + 255) / 256, 256, 0, stream>>>(dis);
    k_deg<<<(ETOT + 255) / 256, 256, 0, stream>>>(ei, dis);
    k_scan<<<1, 256, 0, stream>>>(dis, row0, cnt);
    k_dis<<<(NODES + 255) / 256, 256, 0, stream>>>(dis);
    k_fill<<<(ETOT + 255) / 256, 256, 0, stream>>>(ei, dis, row0, cnt, edge8);
    k_prep<<<(192 * 64 + 255) / 256, 256, 0, stream>>>(w_hh_e, w_hh_d, WtE, WtD);

    // fused encoder: single launch, h resident in LDS across all 24 steps
    k_encf<<<NBLK, 256, 0, stream>>>(pm, w_ih_e, WtE, b_ih_e, b_hh_e,
                                     fc_w, fc_b, hA, Hb);
    k_fc<<<NODES / 256, 256, 0, stream>>>(hA, fc_w, fc_b, feat, cw1, xn, y1);

    // decoder: fused gather+GRU, then attention, per step
    for (int t = 0; t < TF; t++) {
        const float* hin = (t & 1) ? hB : hA;
        float* hout      = (t & 1) ? hA : hB;
        k_dec<<<NBLK, 256, 0, stream>>>(feat, w_ih_d, WtD, b_ih_d, b_hh_d,
                                        cw0, cb, xn, y1, row0, edge8,
                                        hin, hout, h_nm, t);
        k_attn<<<NODES / 4, 256, 0, stream>>>(Hb, h_nm, out_w, out_b, feat, cw1,
                                              xn, y1, out, t);
    }
}

// Round 8
// 1202.280 us; speedup vs baseline: 1.6036x; 1.6036x over previous
//
#include <hip/hip_runtime.h>
#include <hip/hip_bf16.h>
#include <cstddef>
#include <cstdint>

// Problem constants
constexpr int NB    = 16;
constexpr int NN    = 2000;
constexpr int TH    = 24;
constexpr int TF    = 24;
constexpr int HID   = 64;
constexpr int NF    = 8;
constexpr int NODES = NB * NN;      // 32000
constexpr int ETOT  = NODES * 32;   // 1,024,000
constexpr int TT    = TH + TF;      // 48
constexpr int BLKN  = 64;           // nodes per MFMA block
constexpr int NBLK  = NODES / BLKN; // 500

typedef __attribute__((ext_vector_type(8))) short bf16x8;
typedef __attribute__((ext_vector_type(4))) float f32x4;
typedef uint16_t u16;

__device__ __forceinline__ float sigmoidf_(float x) { return 1.f / (1.f + __expf(-x)); }
__device__ __forceinline__ float tanhf_(float x) {
    float e = __expf(2.f * x);
    return 1.f - 2.f / (e + 1.f);
}
__device__ __forceinline__ u16 bfh(float x) {
    __hip_bfloat16 b = __float2bfloat16(x);
    u16 u; __builtin_memcpy(&u, &b, 2); return u;
}
__device__ __forceinline__ float bff(u16 u) { return __uint_as_float(((uint32_t)u) << 16); }
__device__ __forceinline__ uint32_t pk(u16 a, u16 b) { return (uint32_t)a | ((uint32_t)b << 16); }

// ---------------- setup kernels ----------------
__global__ void k_init(float* __restrict__ dis) {
    int i = blockIdx.x * blockDim.x + threadIdx.x;
    if (i < NODES) dis[i] = 0.f;
}

__global__ void k_deg(const int* __restrict__ ei, float* __restrict__ deg) {
    int e = blockIdx.x * blockDim.x + threadIdx.x;
    if (e < ETOT) atomicAdd(&deg[ei[ETOT + e]], 1.0f);
}

__global__ __launch_bounds__(256) void k_scan(const float* __restrict__ degf,
                                              int* __restrict__ row0,
                                              int* __restrict__ cnt)
{
    __shared__ int part[256];
    const int tid = threadIdx.x;
    const int per = NODES / 256;
    const int base = tid * per;
    int s = 0;
    for (int i = 0; i < per; i++) s += (int)degf[base + i];
    part[tid] = s;
    __syncthreads();
    for (int off = 1; off < 256; off <<= 1) {
        int v = (tid >= off) ? part[tid - off] : 0;
        __syncthreads();
        part[tid] += v;
        __syncthreads();
    }
    int run = (tid == 0) ? 0 : part[tid - 1];
    for (int i = 0; i < per; i++) {
        row0[base + i] = run;
        cnt[base + i]  = 0;
        run += (int)degf[base + i];
    }
    if (tid == 255) row0[NODES] = run;
}

__global__ void k_dis(float* __restrict__ dis) {
    int i = blockIdx.x * blockDim.x + threadIdx.x;
    if (i < NODES) {
        float d = dis[i];
        dis[i] = (d > 0.f) ? rsqrtf(fmaxf(d, 1.f)) : 0.f;
    }
}

__global__ void k_fill(const int* __restrict__ ei, const float* __restrict__ dis,
                       const int* __restrict__ row0, int* __restrict__ cnt,
                       int2* __restrict__ edge8)
{
    int e = blockIdx.x * blockDim.x + threadIdx.x;
    if (e < ETOT) {
        int s = ei[e];
        int d = ei[ETOT + e];
        float nv = -(dis[s] * dis[d]);
        int p = atomicAdd(&cnt[d], 1);
        edge8[row0[d] + p] = make_int2(s, __float_as_int(nv));
    }
}

// Encoder A matrix: [208][64] rows 0..191 = w_hh_enc, 192 = fc_w, rest 0. bf16 hi/lo.
__global__ void k_prepE(const float* __restrict__ whe, const float* __restrict__ fcw,
                        u16* __restrict__ AH, u16* __restrict__ AL)
{
    int i = blockIdx.x * blockDim.x + threadIdx.x;
    if (i < 208 * 64) {
        int r = i >> 6, k = i & 63;
        float v = (r < 192) ? whe[r * 64 + k] : ((r == 192) ? fcw[k] : 0.f);
        u16 hi = bfh(v);
        AH[i] = hi;
        AL[i] = bfh(v - bff(hi));
    }
}

// Decoder A matrix: [256][96].
// rows 0..63 (r-gate):  cols 0..63 = Whh_r,  64..73 = Wih_r
// rows 64..127 (z):     cols 0..63 = Whh_z,  64..73 = Wih_z
// rows 128..191 (gh_n): cols 0..63 = Whh_n,  else 0
// rows 192..255 (gi_n): cols 64..73 = Wih_n, else 0
__global__ void k_prepD(const float* __restrict__ whd, const float* __restrict__ wihd,
                        u16* __restrict__ AH, u16* __restrict__ AL)
{
    int i = blockIdx.x * blockDim.x + threadIdx.x;
    if (i < 256 * 96) {
        int r = i / 96, k = i - r * 96;
        float v = 0.f;
        if (k < 64) {
            if (r < 192) v = whd[r * 64 + k];
        } else if (k < 74) {
            int xi = k - 64;
            if (r < 128)       v = wihd[r * 10 + xi];
            else if (r >= 192) v = wihd[(r - 64) * 10 + xi];
        }
        u16 hi = bfh(v);
        AH[i] = hi;
        AL[i] = bfh(v - bff(hi));
    }
}

// ---------------- fused MFMA encoder: all 24 steps, one launch ----------------
// Block = 64 nodes, 4 waves. B operand (h) in LDS bf16 hi/lo, XOR-swizzled,
// double-buffered. Wave wv owns channels 16wv..16wv+15 (rowtiles wv, wv+4, wv+8);
// wave 0 additionally owns rowtile 12 = fc row (xn).
__global__ __launch_bounds__(256, 2) void k_encM(
    const float* __restrict__ pm, const u16* __restrict__ AeH, const u16* __restrict__ AeL,
    const float* __restrict__ w_ih, const float* __restrict__ b_ih, const float* __restrict__ b_hh,
    const float* __restrict__ fc_b, const float* __restrict__ feat, const float* __restrict__ cw1,
    u16* __restrict__ BgH, u16* __restrict__ BgL, u16* __restrict__ Hb,
    float* __restrict__ xn_buf, float* __restrict__ y1)
{
    __shared__ u16 BH[2][64 * 64], BL[2][64 * 64];
    __shared__ float pmL[TH * BLKN];
    __shared__ float xnL[BLKN];

    const int tid = threadIdx.x;
    const int l   = tid & 63;
    const int wv  = __builtin_amdgcn_readfirstlane(tid >> 6);
    const int n0  = blockIdx.x * BLKN;
    const int cn  = l & 15;          // col-in-tile (node) / row-in-tile (A)
    const int kg  = l >> 4;          // k-group
    const int c0  = wv * 16 + kg * 4;

    // zero B buffer 0 (h0 = 0)
    for (int i = tid; i < 64 * 64 / 2; i += 256) {
        ((uint32_t*)BH[0])[i] = 0u;
        ((uint32_t*)BL[0])[i] = 0u;
    }
    // stage pm for all 24 steps
    for (int i = tid; i < TH * BLKN; i += 256) {
        int t = i >> 6, n = i & 63;
        int node = n0 + n, b = node / NN, nn2 = node - b * NN;
        pmL[i] = pm[(b * TH + t) * NN + nn2];
    }
    // A fragments (resident across steps)
    bf16x8 AHf[4][2], ALf[4][2];
    #pragma unroll
    for (int s = 0; s < 4; s++) {
        #pragma unroll
        for (int ks = 0; ks < 2; ks++) {
            bf16x8 zh = {0,0,0,0,0,0,0,0};
            AHf[s][ks] = zh; ALf[s][ks] = zh;
            if (s < 3 || wv == 0) {
                int row = (wv + 4 * s) * 16 + cn;
                int off = row * 64 + ks * 32 + kg * 8;
                AHf[s][ks] = *(const bf16x8*)(AeH + off);
                ALf[s][ks] = *(const bf16x8*)(AeL + off);
            }
        }
    }
    // hoisted per-lane gate params
    float bR[4], bZ[4], biN[4], bhN[4];
    float wR0[4], wR1[4], wZ0[4], wZ1[4], wN0[4], wN1[4];
    #pragma unroll
    for (int j = 0; j < 4; j++) {
        int c = c0 + j;
        bR[j]  = b_ih[c] + b_hh[c];
        bZ[j]  = b_ih[64 + c] + b_hh[64 + c];
        biN[j] = b_ih[128 + c];
        bhN[j] = b_hh[128 + c];
        wR0[j] = w_ih[2 * c];           wR1[j] = w_ih[2 * c + 1];
        wZ0[j] = w_ih[2 * (64 + c)];    wZ1[j] = w_ih[2 * (64 + c) + 1];
        wN0[j] = w_ih[2 * (128 + c)];   wN1[j] = w_ih[2 * (128 + c) + 1];
    }
    const float fcb = fc_b[0];
    __syncthreads();

    for (int t = 0; t < TH; t++) {
        const int cur = t & 1, nxt = cur ^ 1;
        f32x4 acc[4][4];
        #pragma unroll
        for (int s = 0; s < 4; s++)
            #pragma unroll
            for (int ct = 0; ct < 4; ct++)
                acc[s][ct] = (f32x4){0.f, 0.f, 0.f, 0.f};

        #pragma unroll
        for (int ct = 0; ct < 4; ct++) {
            const int n = ct * 16 + cn;
            #pragma unroll
            for (int ks = 0; ks < 2; ks++) {
                const int idx = (n * 64 + ks * 32 + kg * 8) ^ ((n & 7) << 3);
                bf16x8 bh = *(const bf16x8*)&BH[cur][idx];
                bf16x8 bl = *(const bf16x8*)&BL[cur][idx];
                #pragma unroll
                for (int s = 0; s < 4; s++) {
                    if (s < 3 || wv == 0) {
                        acc[s][ct] = __builtin_amdgcn_mfma_f32_16x16x32_bf16(AHf[s][ks], bh, acc[s][ct], 0, 0, 0);
                        acc[s][ct] = __builtin_amdgcn_mfma_f32_16x16x32_bf16(AHf[s][ks], bl, acc[s][ct], 0, 0, 0);
                        acc[s][ct] = __builtin_amdgcn_mfma_f32_16x16x32_bf16(ALf[s][ks], bh, acc[s][ct], 0, 0, 0);
                    }
                }
            }
        }
        if (wv == 0 && kg == 0) {
            #pragma unroll
            for (int ct = 0; ct < 4; ct++) xnL[ct * 16 + cn] = acc[3][ct][0];
        }
        __syncthreads();   // xn visible; all frag reads of BH[cur] done

        #pragma unroll
        for (int ct = 0; ct < 4; ct++) {
            const int n = ct * 16 + cn, node = n0 + n;
            float xn = 0.f;
            if (t > 0) xn = xnL[n] + fcb;
            const float pv = pmL[t * 64 + n];
            const int hidx = (n * 64 + c0) ^ ((n & 7) << 3);
            uint2 oh = *(const uint2*)&BH[cur][hidx];
            uint2 ol = *(const uint2*)&BL[cur][hidx];
            float hnew[4];
            #pragma unroll
            for (int j = 0; j < 4; j++) {
                u16 hh = (j < 2) ? (u16)((j == 0) ? (oh.x & 0xffff) : (oh.x >> 16))
                                 : (u16)((j == 2) ? (oh.y & 0xffff) : (oh.y >> 16));
                u16 ll = (j < 2) ? (u16)((j == 0) ? (ol.x & 0xffff) : (ol.x >> 16))
                                 : (u16)((j == 2) ? (ol.y & 0xffff) : (ol.y >> 16));
                float hold = bff(hh) + bff(ll);
                float r  = sigmoidf_(acc[0][ct][j] + bR[j] + wR0[j] * xn + wR1[j] * pv);
                float z  = sigmoidf_(acc[1][ct][j] + bZ[j] + wZ0[j] * xn + wZ1[j] * pv);
                float gi = biN[j] + wN0[j] * xn + wN1[j] * pv;
                float gh = acc[2][ct][j] + bhN[j];
                float nn_ = tanhf_(gi + r * gh);
                hnew[j] = (1.f - z) * nn_ + z * hold;
            }
            u16 nh0 = bfh(hnew[0]), nh1 = bfh(hnew[1]), nh2 = bfh(hnew[2]), nh3 = bfh(hnew[3]);
            u16 nl0 = bfh(hnew[0] - bff(nh0)), nl1 = bfh(hnew[1] - bff(nh1));
            u16 nl2 = bfh(hnew[2] - bff(nh2)), nl3 = bfh(hnew[3] - bff(nh3));
            uint2 ph = make_uint2(pk(nh0, nh1), pk(nh2, nh3));
            uint2 pl = make_uint2(pk(nl0, nl1), pk(nl2, nl3));
            *(uint2*)&BH[nxt][hidx] = ph;
            *(uint2*)&BL[nxt][hidx] = pl;
            *(uint2*)(Hb + (size_t)node * (TH * HID) + t * HID + c0) = ph;
        }
        __syncthreads();   // B[nxt] complete
    }

    // final h is in buffer 0.  xn_final = fc(h_24) via fc-row MFMA (wave 0)
    if (wv == 0) {
        f32x4 ax[4];
        #pragma unroll
        for (int ct = 0; ct < 4; ct++) ax[ct] = (f32x4){0.f, 0.f, 0.f, 0.f};
        #pragma unroll
        for (int ct = 0; ct < 4; ct++) {
            const int n = ct * 16 + cn;
            #pragma unroll
            for (int ks = 0; ks < 2; ks++) {
                const int idx = (n * 64 + ks * 32 + kg * 8) ^ ((n & 7) << 3);
                bf16x8 bh = *(const bf16x8*)&BH[0][idx];
                bf16x8 bl = *(const bf16x8*)&BL[0][idx];
                ax[ct] = __builtin_amdgcn_mfma_f32_16x16x32_bf16(AHf[3][ks], bh, ax[ct], 0, 0, 0);
                ax[ct] = __builtin_amdgcn_mfma_f32_16x16x32_bf16(AHf[3][ks], bl, ax[ct], 0, 0, 0);
                ax[ct] = __builtin_amdgcn_mfma_f32_16x16x32_bf16(ALf[3][ks], bh, ax[ct], 0, 0, 0);
            }
        }
        if (kg == 0) {
            #pragma unroll
            for (int ct = 0; ct < 4; ct++) xnL[ct * 16 + cn] = ax[ct][0];
        }
    }
    __syncthreads();

    // export final h (hi/lo) to global + xn_buf + y1 for decoder t=0
    for (int i = tid; i < 512; i += 256) {
        int n = i >> 3, sl = i & 7;
        int idx = (n * 64 + sl * 8) ^ ((n & 7) << 3);
        *(uint4*)(BgH + ((size_t)(n0 + n)) * 64 + sl * 8) = *(const uint4*)&BH[0][idx];
        *(uint4*)(BgL + ((size_t)(n0 + n)) * 64 + sl * 8) = *(const uint4*)&BL[0][idx];
    }
    if (tid < BLKN) {
        int n = tid, node = n0 + n;
        float xv = xnL[n] + fcb;
        xn_buf[node] = xv;
        int b = node / NN, nn2 = node - b * NN;
        const float* fp = feat + ((size_t)(b * TT + TH) * NN + nn2) * NF;
        float yy = xv * cw1[0];
        #pragma unroll
        for (int q = 0; q < NF; q++) yy += fp[q] * cw1[1 + q];
        y1[node] = yy;
    }
}

// ---------------- CSR gather (unchanged) ----------------
__global__ __launch_bounds__(256) void k_gather(
    const int* __restrict__ row0, const int2* __restrict__ edge8,
    const float* __restrict__ y1, float* __restrict__ tx)
{
    const int tid  = blockIdx.x * 256 + threadIdx.x;
    const int node = tid >> 2;
    const int q    = tid & 3;
    if (node >= NODES) return;
    const int beg = row0[node], end = row0[node + 1];
    float acc = 0.f;
    for (int i = beg + q; i < end; i += 4) {
        const int2 e = edge8[i];
        acc = fmaf(__int_as_float(e.y), y1[e.x], acc);
    }
    acc += __shfl_xor(acc, 1, 64);
    acc += __shfl_xor(acc, 2, 64);
    if (q == 0) tx[node] = acc;
}

// ---------------- MFMA decoder step ----------------
// K = 96: k 0..63 = h (hi/lo), 64..73 = x = [xn, f0..7, xg], 74..95 = 0.
// M = 256: r rows, z rows, gh_n rows, gi_n rows. Wave wv: rowtiles wv+4s.
__global__ __launch_bounds__(256, 2) void k_decM(
    const float* __restrict__ feat, const u16* __restrict__ AdH, const u16* __restrict__ AdL,
    const float* __restrict__ b_ih, const float* __restrict__ b_hh,
    const float* __restrict__ w0, const float* __restrict__ cb,
    const float* __restrict__ xn_buf, const float* __restrict__ tx,
    const u16* __restrict__ BgHin, const u16* __restrict__ BgLin,
    u16* __restrict__ BgHout, u16* __restrict__ BgLout, int t)
{
    __shared__ u16 XH[64 * 96], XL[64 * 96];
    const int tid = threadIdx.x;
    const int l   = tid & 63;
    const int wv  = __builtin_amdgcn_readfirstlane(tid >> 6);
    const int n0  = blockIdx.x * BLKN;
    const int cn  = l & 15, kg = l >> 4;
    const int c0  = wv * 16 + kg * 4;

    // stage h rows (global [n][64] -> LDS [n][96] swizzled)
    for (int i = tid; i < 512; i += 256) {
        int n = i >> 3, sl = i & 7;
        int idx = (n * 96 + sl * 8) ^ ((n & 7) << 3);
        *(uint4*)&XH[idx] = *(const uint4*)(BgHin + ((size_t)(n0 + n)) * 64 + sl * 8);
        *(uint4*)&XL[idx] = *(const uint4*)(BgLin + ((size_t)(n0 + n)) * 64 + sl * 8);
    }
    // stage x rows (k=64..95)
    if (tid < BLKN) {
        int n = tid, node = n0 + n;
        int b = node / NN, nn2 = node - b * NN;
        float x0 = xn_buf[node];
        const float* fp = feat + ((size_t)(b * TT + TH + t) * NN + nn2) * NF;
        float f0 = fp[0], f1 = fp[1], f2 = fp[2], f3 = fp[3];
        float f4 = fp[4], f5 = fp[5], f6 = fp[6], f7 = fp[7];
        float xw = x0 * w0[0];
        xw = fmaf(f0, w0[1], xw); xw = fmaf(f1, w0[2], xw);
        xw = fmaf(f2, w0[3], xw); xw = fmaf(f3, w0[4], xw);
        xw = fmaf(f4, w0[5], xw); xw = fmaf(f5, w0[6], xw);
        xw = fmaf(f6, w0[7], xw); xw = fmaf(f7, w0[8], xw);
        float xg = sigmoidf_(xw + tx[node] + cb[0]);
        u16 h0 = bfh(x0), h1 = bfh(f0), h2 = bfh(f1), h3 = bfh(f2), h4 = bfh(f3);
        u16 h5 = bfh(f4), h6 = bfh(f5), h7 = bfh(f6), h8 = bfh(f7), h9 = bfh(xg);
        u16 l0 = bfh(x0 - bff(h0)), l1 = bfh(f0 - bff(h1)), l2 = bfh(f1 - bff(h2));
        u16 l3 = bfh(f2 - bff(h3)), l4 = bfh(f3 - bff(h4)), l5 = bfh(f4 - bff(h5));
        u16 l6 = bfh(f5 - bff(h6)), l7 = bfh(f6 - bff(h7)), l8 = bfh(f7 - bff(h8));
        u16 l9 = bfh(xg - bff(h9));
        uint4 qh0 = make_uint4(pk(h0, h1), pk(h2, h3), pk(h4, h5), pk(h6, h7));
        uint4 qh1 = make_uint4(pk(h8, h9), 0u, 0u, 0u);
        uint4 ql0 = make_uint4(pk(l0, l1), pk(l2, l3), pk(l4, l5), pk(l6, l7));
        uint4 ql1 = make_uint4(pk(l8, l9), 0u, 0u, 0u);
        uint4 zz  = make_uint4(0u, 0u, 0u, 0u);
        const int sw = (n & 7) << 3;
        *(uint4*)&XH[(n * 96 + 64) ^ sw] = qh0;
        *(uint4*)&XH[(n * 96 + 72) ^ sw] = qh1;
        *(uint4*)&XH[(n * 96 + 80) ^ sw] = zz;
        *(uint4*)&XH[(n * 96 + 88) ^ sw] = zz;
        *(uint4*)&XL[(n * 96 + 64) ^ sw] = ql0;
        *(uint4*)&XL[(n * 96 + 72) ^ sw] = ql1;
        *(uint4*)&XL[(n * 96 + 80) ^ sw] = zz;
        *(uint4*)&XL[(n * 96 + 88) ^ sw] = zz;
    }
    // hoisted biases
    float bsR[4], bsZ[4], biN[4], bhN[4];
    #pragma unroll
    for (int j = 0; j < 4; j++) {
        int c = c0 + j;
        bsR[j] = b_ih[c] + b_hh[c];
        bsZ[j] = b_ih[64 + c] + b_hh[64 + c];
        biN[j] = b_ih[128 + c];
        bhN[j] = b_hh[128 + c];
    }
    // A fragments (live set: s0,s1 all ks; s2 ks0,1; s3 ks2)
    bf16x8 AHf[4][3], ALf[4][3];
    #pragma unroll
    for (int s = 0; s < 4; s++) {
        #pragma unroll
        for (int ks = 0; ks < 3; ks++) {
            bf16x8 zh = {0,0,0,0,0,0,0,0};
            AHf[s][ks] = zh; ALf[s][ks] = zh;
            const bool live = (s < 2) || (s == 2 && ks < 2) || (s == 3 && ks == 2);
            if (live) {
                int row = (wv + 4 * s) * 16 + cn;
                int off = row * 96 + ks * 32 + kg * 8;
                AHf[s][ks] = *(const bf16x8*)(AdH + off);
                ALf[s][ks] = *(const bf16x8*)(AdL + off);
            }
        }
    }
    __syncthreads();

    f32x4 acc[4][4];
    #pragma unroll
    for (int s = 0; s < 4; s++)
        #pragma unroll
        for (int ct = 0; ct < 4; ct++)
            acc[s][ct] = (f32x4){0.f, 0.f, 0.f, 0.f};

    #pragma unroll
    for (int ct = 0; ct < 4; ct++) {
        const int n = ct * 16 + cn;
        #pragma unroll
        for (int ks = 0; ks < 3; ks++) {
            const int idx = (n * 96 + ks * 32 + kg * 8) ^ ((n & 7) << 3);
            bf16x8 bh = *(const bf16x8*)&XH[idx];
            bf16x8 bl = *(const bf16x8*)&XL[idx];
            #pragma unroll
            for (int s = 0; s < 4; s++) {
                const bool live = (s < 2) || (s == 2 && ks < 2) || (s == 3 && ks == 2);
                if (live) {
                    acc[s][ct] = __builtin_amdgcn_mfma_f32_16x16x32_bf16(AHf[s][ks], bh, acc[s][ct], 0, 0, 0);
                    acc[s][ct] = __builtin_amdgcn_mfma_f32_16x16x32_bf16(AHf[s][ks], bl, acc[s][ct], 0, 0, 0);
                    acc[s][ct] = __builtin_amdgcn_mfma_f32_16x16x32_bf16(ALf[s][ks], bh, acc[s][ct], 0, 0, 0);
                }
            }
        }
    }

    // epilogue: r = σ(accR+b), z = σ(accZ+b), n = tanh(gi_n + r*gh_n), h' = (1-z)n + z h
    #pragma unroll
    for (int ct = 0; ct < 4; ct++) {
        const int n = ct * 16 + cn, node = n0 + n;
        const int hidx = (n * 96 + c0) ^ ((n & 7) << 3);
        uint2 oh = *(const uint2*)&XH[hidx];
        uint2 ol = *(const uint2*)&XL[hidx];
        float hnew[4];
        #pragma unroll
        for (int j = 0; j < 4; j++) {
            u16 hh = (j < 2) ? (u16)((j == 0) ? (oh.x & 0xffff) : (oh.x >> 16))
                             : (u16)((j == 2) ? (oh.y & 0xffff) : (oh.y >> 16));
            u16 ll = (j < 2) ? (u16)((j == 0) ? (ol.x & 0xffff) : (ol.x >> 16))
                             : (u16)((j == 2) ? (ol.y & 0xffff) : (ol.y >> 16));
            float hold = bff(hh) + bff(ll);
            float r  = sigmoidf_(acc[0][ct][j] + bsR[j]);
            float z  = sigmoidf_(acc[1][ct][j] + bsZ[j]);
            float nn_ = tanhf_((acc[3][ct][j] + biN[j]) + r * (acc[2][ct][j] + bhN[j]));
            hnew[j] = (1.f - z) * nn_ + z * hold;
        }
        u16 nh0 = bfh(hnew[0]), nh1 = bfh(hnew[1]), nh2 = bfh(hnew[2]), nh3 = bfh(hnew[3]);
        u16 nl0 = bfh(hnew[0] - bff(nh0)), nl1 = bfh(hnew[1] - bff(nh1));
        u16 nl2 = bfh(hnew[2] - bff(nh2)), nl3 = bfh(hnew[3] - bff(nh3));
        *(uint2*)(BgHout + (size_t)node * 64 + c0) = make_uint2(pk(nh0, nh1), pk(nh2, nh3));
        *(uint2*)(BgLout + (size_t)node * 64 + c0) = make_uint2(pk(nl0, nl1), pk(nl2, nl3));
    }
}

// ---------------- attention (h read as bf16 hi+lo) ----------------
__global__ __launch_bounds__(256) void k_attn(
    const u16* __restrict__ Hb, const u16* __restrict__ BgH, const u16* __restrict__ BgL,
    const float* __restrict__ out_w, const float* __restrict__ out_b,
    const float* __restrict__ feat, const float* __restrict__ cw1,
    float* __restrict__ xn_buf, float* __restrict__ y1,
    float* __restrict__ out, int t)
{
    const int wid  = threadIdx.x >> 6;
    const int lane = threadIdx.x & 63;
    const int node = blockIdx.x * 4 + wid;
    if (node >= NODES) return;
    const int d0 = (lane & 7) * 8;

    const float hj = bff(BgH[(size_t)node * 64 + lane]) + bff(BgL[(size_t)node * 64 + lane]);
    float hval[8];
    #pragma unroll
    for (int q = 0; q < 8; q++) hval[q] = __shfl(hj, d0 + q, 64);

    const uint4* Hrow = (const uint4*)(Hb + (size_t)node * (TH * HID));
    float Hf[3][8];
    float er[3];
    #pragma unroll
    for (int R = 0; R < 3; R++) {
        const uint4 v = Hrow[R * 64 + lane];
        const uint32_t u0 = v.x, u1 = v.y, u2 = v.z, u3 = v.w;
        Hf[R][0] = __uint_as_float(u0 << 16);
        Hf[R][1] = __uint_as_float(u0 & 0xffff0000u);
        Hf[R][2] = __uint_as_float(u1 << 16);
        Hf[R][3] = __uint_as_float(u1 & 0xffff0000u);
        Hf[R][4] = __uint_as_float(u2 << 16);
        Hf[R][5] = __uint_as_float(u2 & 0xffff0000u);
        Hf[R][6] = __uint_as_float(u3 << 16);
        Hf[R][7] = __uint_as_float(u3 & 0xffff0000u);
        float part = 0.f;
        #pragma unroll
        for (int q = 0; q < 8; q++) part = fmaf(Hf[R][q], hval[q], part);
        part += __shfl_xor(part, 1, 64);
        part += __shfl_xor(part, 2, 64);
        part += __shfl_xor(part, 4, 64);
        er[R] = part;
    }

    float m = fmaxf(fmaxf(er[0], er[1]), er[2]);
    m = fmaxf(m, __shfl_xor(m, 8, 64));
    m = fmaxf(m, __shfl_xor(m, 16, 64));
    m = fmaxf(m, __shfl_xor(m, 32, 64));

    float w0_ = __expf(er[0] - m);
    float w1_ = __expf(er[1] - m);
    float w2_ = __expf(er[2] - m);
    float s = w0_ + w1_ + w2_;
    s += __shfl_xor(s, 8, 64);
    s += __shfl_xor(s, 16, 64);
    s += __shfl_xor(s, 32, 64);
    const float rs = 1.f / s;

    float aq[8];
    #pragma unroll
    for (int q = 0; q < 8; q++) {
        float a = w0_ * Hf[0][q];
        a = fmaf(w1_, Hf[1][q], a);
        a = fmaf(w2_, Hf[2][q], a);
        a += __shfl_xor(a, 8, 64);
        a += __shfl_xor(a, 16, 64);
        a += __shfl_xor(a, 32, 64);
        aq[q] = a * rs;
    }

    float part = 0.f;
    #pragma unroll
    for (int q = 0; q < 8; q++) {
        part = fmaf(out_w[d0 + q],       aq[q],   part);
        part = fmaf(out_w[HID + d0 + q], hval[q], part);
    }
    part += __shfl_xor(part, 1, 64);
    part += __shfl_xor(part, 2, 64);
    part += __shfl_xor(part, 4, 64);
    const float xnew = part + out_b[0];

    if (lane == 0) {
        const int b = node / NN, n = node - b * NN;
        out[(b * TF + t) * NN + n] = xnew;
        xn_buf[node] = xnew;
        if (t + 1 < TF) {
            const float* fp = feat + ((size_t)(b * TT + TH + t + 1) * NN + n) * NF;
            float yy = xnew * cw1[0];
            #pragma unroll
            for (int c = 0; c < NF; c++) yy += fp[c] * cw1[1 + c];
            y1[node] = yy;
        }
    }
}

// ---------------- host launch ----------------
extern "C" void kernel_launch(void* const* d_in, const int* in_sizes, int n_in,
                              void* d_out, int out_size, void* d_ws, size_t ws_size,
                              hipStream_t stream)
{
    const float* pm     = (const float*)d_in[0];
    const float* feat   = (const float*)d_in[1];
    const int*   ei     = (const int*)d_in[2];
    const float* w_ih_e = (const float*)d_in[3];
    const float* w_hh_e = (const float*)d_in[4];
    const float* b_ih_e = (const float*)d_in[5];
    const float* b_hh_e = (const float*)d_in[6];
    const float* fc_w   = (const float*)d_in[7];
    const float* fc_b   = (const float*)d_in[8];
    const float* cw0    = (const float*)d_in[9];
    const float* cw1    = (const float*)d_in[10];
    const float* cb     = (const float*)d_in[11];
    const float* w_ih_d = (const float*)d_in[12];
    const float* w_hh_d = (const float*)d_in[13];
    const float* b_ih_d = (const float*)d_in[14];
    const float* b_hh_d = (const float*)d_in[15];
    const float* out_w  = (const float*)d_in[16];
    const float* out_b  = (const float*)d_in[17];
    float* out = (float*)d_out;

    char* ws = (char*)d_ws;
    size_t off = 0;
    auto alloc = [&](size_t bytes) -> void* {
        void* p = ws + off;
        off += (bytes + 255) & ~(size_t)255;
        return p;
    };
    u16* Hb    = (u16*)alloc(sizeof(u16) * (size_t)NODES * TH * HID);
    u16* BgAH  = (u16*)alloc(sizeof(u16) * (size_t)NODES * HID);
    u16* BgAL  = (u16*)alloc(sizeof(u16) * (size_t)NODES * HID);
    u16* BgBH  = (u16*)alloc(sizeof(u16) * (size_t)NODES * HID);
    u16* BgBL  = (u16*)alloc(sizeof(u16) * (size_t)NODES * HID);
    float* xn  = (float*)alloc(sizeof(float) * NODES);
    float* dis = (float*)alloc(sizeof(float) * NODES);
    float* y1  = (float*)alloc(sizeof(float) * NODES);
    float* tx  = (float*)alloc(sizeof(float) * NODES);
    u16* AeH   = (u16*)alloc(sizeof(u16) * 208 * 64);
    u16* AeL   = (u16*)alloc(sizeof(u16) * 208 * 64);
    u16* AdH   = (u16*)alloc(sizeof(u16) * 256 * 96);
    u16* AdL   = (u16*)alloc(sizeof(u16) * 256 * 96);
    int* row0  = (int*)alloc(sizeof(int) * (NODES + 1));
    int* cnt   = (int*)alloc(sizeof(int) * NODES);
    int2* edge8 = (int2*)alloc(sizeof(int2) * ETOT);
    if (off > ws_size) return;

    // setup
    k_init<<<(NODES + 255) / 256, 256, 0, stream>>>(dis);
    k_deg<<<(ETOT + 255) / 256, 256, 0, stream>>>(ei, dis);
    k_scan<<<1, 256, 0, stream>>>(dis, row0, cnt);
    k_dis<<<(NODES + 255) / 256, 256, 0, stream>>>(dis);
    k_fill<<<(ETOT + 255) / 256, 256, 0, stream>>>(ei, dis, row0, cnt, edge8);
    k_prepE<<<(208 * 64 + 255) / 256, 256, 0, stream>>>(w_hh_e, fc_w, AeH, AeL);
    k_prepD<<<(256 * 96 + 255) / 256, 256, 0, stream>>>(w_hh_d, w_ih_d, AdH, AdL);

    // fused MFMA encoder (writes Hb, final h -> BgA, xn_buf, y1)
    k_encM<<<NBLK, 256, 0, stream>>>(pm, AeH, AeL, w_ih_e, b_ih_e, b_hh_e,
                                     fc_b, feat, cw1, BgAH, BgAL, Hb, xn, y1);

    // decoder
    for (int t = 0; t < TF; t++) {
        const u16* inH = (t & 1) ? BgBH : BgAH;
        const u16* inL = (t & 1) ? BgBL : BgAL;
        u16* outH      = (t & 1) ? BgAH : BgBH;
        u16* outL      = (t & 1) ? BgAL : BgBL;
        k_gather<<<(NODES * 4) / 256, 256, 0, stream>>>(row0, edge8, y1, tx);
        k_decM<<<NBLK, 256, 0, stream>>>(feat, AdH, AdL, b_ih_d, b_hh_d,
                                         cw0, cb, xn, tx, inH, inL, outH, outL, t);
        k_attn<<<NODES / 4, 256, 0, stream>>>(Hb, outH, outL, out_w, out_b, feat, cw1,
                                              xn, y1, out, t);
    }
}